// Round 4
// baseline (758.414 us; speedup 1.0000x reference)
//
#include <hip/hip_runtime.h>

#define KT 4
#define KN 20000        // NA == ND == 20000
#define KE 100000
#define KH 128
#define KL 2
#define KNT 40000       // NA + ND

typedef __attribute__((ext_vector_type(8))) short short8v;
typedef __attribute__((ext_vector_type(4))) float f32x4;

__device__ __forceinline__ short bf16rn(float x) {
    unsigned u = __float_as_uint(x);
    u = (u + 0x7fffu + ((u >> 16) & 1u)) >> 16;
    return (short)u;
}
__device__ __forceinline__ float bf16tof(short h) {
    return __uint_as_float(((unsigned)(unsigned short)h) << 16);
}

// ---------------------------------------------------------------------------
// CSR build: counts -> scan -> fill (packed (edge, src) pairs).
// ---------------------------------------------------------------------------
__global__ void count_k(const int* __restrict__ ei_ad, const int* __restrict__ ei_da,
                        int* __restrict__ cnt) {
    int e = blockIdx.x * 256 + threadIdx.x;
    int z = blockIdx.y;                 // z = t*2 + et
    if (e >= KE) return;
    int t = z >> 1, et = z & 1;
    const int* ei = et ? ei_da : ei_ad;
    int dst = ei[(t * 2 + 1) * KE + e];
    atomicAdd(&cnt[z * KN + dst], 1);
}

__global__ void scan_k(int* __restrict__ cnt, int* __restrict__ offs) {
    __shared__ int s[256];
    int z = blockIdx.x, tid = threadIdx.x;
    const int CH = (KN + 255) / 256;    // 79
    int n0 = tid * CH;
    int lim = n0 < KN ? min(CH, KN - n0) : 0;
    long base = (long)z * KN + n0;
    int sum = 0;
    for (int i = 0; i < lim; ++i) sum += cnt[base + i];
    s[tid] = sum;
    __syncthreads();
    for (int off = 1; off < 256; off <<= 1) {
        int v = (tid >= off) ? s[tid - off] : 0;
        __syncthreads();
        s[tid] += v;
        __syncthreads();
    }
    int run = s[tid] - sum;             // exclusive prefix
    for (int i = 0; i < lim; ++i) {
        int c = cnt[base + i];
        offs[(long)z * (KN + 1) + n0 + i] = run;
        cnt[base + i] = run;            // becomes fill cursor
        run += c;
    }
    if (tid == 0) offs[(long)z * (KN + 1) + KN] = KE;
}

__global__ void fill_k(const int* __restrict__ ei_ad, const int* __restrict__ ei_da,
                       int* __restrict__ cur, int2* __restrict__ pes) {
    int e = blockIdx.x * 256 + threadIdx.x;
    int z = blockIdx.y;
    if (e >= KE) return;
    int t = z >> 1, et = z & 1;
    const int* ei = et ? ei_da : ei_ad;
    int src = ei[(t * 2 + 0) * KE + e];
    int dst = ei[(t * 2 + 1) * KE + e];
    int pos = atomicAdd(&cur[z * KN + dst], 1);
    pes[(long)z * KE + pos] = make_int2(e, src);
}

// ---------------------------------------------------------------------------
// Aggregation: 16-lane group per node (4 nodes/wave), each lane owns 8
// features (2 float4).  4-edge unroll -> 16 independent float4 gathers per
// iteration; pes indices prefetched one iteration ahead.
// ---------------------------------------------------------------------------
__global__ __launch_bounds__(256)
void agg_k(const float* __restrict__ xa_base, long xa_ts,
           const float* __restrict__ xd_base, long xd_ts,
           const float* __restrict__ ea_ad, const float* __restrict__ ea_da,
           const float* __restrict__ eps_ad, const float* __restrict__ eps_da,
           const int* __restrict__ offs, const int2* __restrict__ pes,
           float* __restrict__ agg, int l) {
    int z = blockIdx.y, t = z >> 1, et = z & 1;
    int li = threadIdx.x & 15;
    int node = blockIdx.x * 16 + (threadIdx.x >> 4);   // grid sized exactly

    const float* ea  = (et ? ea_da : ea_ad) + (long)t * KE * KH;
    const float* eps = et ? eps_da : eps_ad;
    const float* src = et ? (xd_base + t * xd_ts) : (xa_base + t * xa_ts);
    const float* dst = et ? (xa_base + t * xa_ts) : (xd_base + t * xd_ts);
    const int2*  pz  = pes + (long)z * KE;

    int beg = offs[(long)z * (KN + 1) + node];
    int end = offs[(long)z * (KN + 1) + node + 1];
    float scale = 1.0f + eps[t * KL + l];

    const float* drow = dst + (long)node * KH + li * 8;
    float4 dv0 = *(const float4*)(drow);
    float4 dv1 = *(const float4*)(drow + 4);

    float4 a0 = make_float4(0.f, 0.f, 0.f, 0.f);
    float4 a1 = make_float4(0.f, 0.f, 0.f, 0.f);

    if (beg < end) {
        int last = end - 1;
        int i = beg;
        int2 q0 = pz[i], q1 = pz[min(i + 1, last)],
             q2 = pz[min(i + 2, last)], q3 = pz[min(i + 3, last)];
        while (i < end) {
            int2 c0 = q0, c1 = q1, c2 = q2, c3 = q3;
            int nx = i + 4;
            if (nx < end) {
                q0 = pz[nx];
                q1 = pz[min(nx + 1, last)];
                q2 = pz[min(nx + 2, last)];
                q3 = pz[min(nx + 3, last)];
            }
            const float* s0 = src + (long)c0.y * KH + li * 8;
            const float* g0 = ea  + (long)c0.x * KH + li * 8;
            const float* s1 = src + (long)c1.y * KH + li * 8;
            const float* g1 = ea  + (long)c1.x * KH + li * 8;
            const float* s2 = src + (long)c2.y * KH + li * 8;
            const float* g2 = ea  + (long)c2.x * KH + li * 8;
            const float* s3 = src + (long)c3.y * KH + li * 8;
            const float* g3 = ea  + (long)c3.x * KH + li * 8;
            float4 x0a = *(const float4*)s0,      x0b = *(const float4*)(s0 + 4);
            float4 e0a = *(const float4*)g0,      e0b = *(const float4*)(g0 + 4);
            float4 x1a = *(const float4*)s1,      x1b = *(const float4*)(s1 + 4);
            float4 e1a = *(const float4*)g1,      e1b = *(const float4*)(g1 + 4);
            float4 x2a = *(const float4*)s2,      x2b = *(const float4*)(s2 + 4);
            float4 e2a = *(const float4*)g2,      e2b = *(const float4*)(g2 + 4);
            float4 x3a = *(const float4*)s3,      x3b = *(const float4*)(s3 + 4);
            float4 e3a = *(const float4*)g3,      e3b = *(const float4*)(g3 + 4);

            a0.x += fmaxf(x0a.x + e0a.x, 0.f); a0.y += fmaxf(x0a.y + e0a.y, 0.f);
            a0.z += fmaxf(x0a.z + e0a.z, 0.f); a0.w += fmaxf(x0a.w + e0a.w, 0.f);
            a1.x += fmaxf(x0b.x + e0b.x, 0.f); a1.y += fmaxf(x0b.y + e0b.y, 0.f);
            a1.z += fmaxf(x0b.z + e0b.z, 0.f); a1.w += fmaxf(x0b.w + e0b.w, 0.f);
            if (i + 1 < end) {
                a0.x += fmaxf(x1a.x + e1a.x, 0.f); a0.y += fmaxf(x1a.y + e1a.y, 0.f);
                a0.z += fmaxf(x1a.z + e1a.z, 0.f); a0.w += fmaxf(x1a.w + e1a.w, 0.f);
                a1.x += fmaxf(x1b.x + e1b.x, 0.f); a1.y += fmaxf(x1b.y + e1b.y, 0.f);
                a1.z += fmaxf(x1b.z + e1b.z, 0.f); a1.w += fmaxf(x1b.w + e1b.w, 0.f);
            }
            if (i + 2 < end) {
                a0.x += fmaxf(x2a.x + e2a.x, 0.f); a0.y += fmaxf(x2a.y + e2a.y, 0.f);
                a0.z += fmaxf(x2a.z + e2a.z, 0.f); a0.w += fmaxf(x2a.w + e2a.w, 0.f);
                a1.x += fmaxf(x2b.x + e2b.x, 0.f); a1.y += fmaxf(x2b.y + e2b.y, 0.f);
                a1.z += fmaxf(x2b.z + e2b.z, 0.f); a1.w += fmaxf(x2b.w + e2b.w, 0.f);
            }
            if (i + 3 < end) {
                a0.x += fmaxf(x3a.x + e3a.x, 0.f); a0.y += fmaxf(x3a.y + e3a.y, 0.f);
                a0.z += fmaxf(x3a.z + e3a.z, 0.f); a0.w += fmaxf(x3a.w + e3a.w, 0.f);
                a1.x += fmaxf(x3b.x + e3b.x, 0.f); a1.y += fmaxf(x3b.y + e3b.y, 0.f);
                a1.z += fmaxf(x3b.z + e3b.z, 0.f); a1.w += fmaxf(x3b.w + e3b.w, 0.f);
            }
            i = nx;
        }
    }

    float4 r0, r1;
    r0.x = scale * dv0.x + a0.x; r0.y = scale * dv0.y + a0.y;
    r0.z = scale * dv0.z + a0.z; r0.w = scale * dv0.w + a0.w;
    r1.x = scale * dv1.x + a1.x; r1.y = scale * dv1.y + a1.y;
    r1.z = scale * dv1.z + a1.z; r1.w = scale * dv1.w + a1.w;
    float* orow = agg + ((long)z * KN + node) * KH + li * 8;
    *(float4*)orow = r0;
    *(float4*)(orow + 4) = r1;
}

// ---------------------------------------------------------------------------
// W pre-split: for each of 32 matrices (4 arrays x T x L), write transposed
// split-bf16 chunks: wsp[((mat*2+h)*4 + kc)*4096 + col*32 + kk]
// where W[k][col], k = kc*32+kk.  h=0: hi, h=1: lo.
// ---------------------------------------------------------------------------
__global__ __launch_bounds__(256)
void wsplit_k(const float* __restrict__ w1_ad, const float* __restrict__ w1_da,
              const float* __restrict__ w2_ad, const float* __restrict__ w2_da,
              short* __restrict__ wsp) {
    int mat = blockIdx.x;                // 0..31
    int arr = mat >> 3, rem = mat & 7;   // rem = t*2+l
    const float* src = (arr == 0 ? w1_ad : arr == 1 ? w1_da : arr == 2 ? w2_ad : w2_da)
                       + (long)rem * KH * KH;
    for (int p = 0; p < 64; ++p) {
        int idx = p * 256 + threadIdx.x; // 16384 elems
        int k = idx >> 7, c = idx & 127;
        float v = src[idx];
        short hi = bf16rn(v);
        short lo = bf16rn(v - bf16tof(hi));
        int chunk = k >> 5, kk = k & 31;
        long ohi = ((long)(mat * 2 + 0) * 4 + chunk) * 4096 + c * 32 + kk;
        long olo = ((long)(mat * 2 + 1) * 4 + chunk) * 4096 + c * 32 + kk;
        wsp[ohi] = hi;
        wsp[olo] = lo;
    }
}

// ---------------------------------------------------------------------------
// MFMA GEMM via bf16-split (3-term Ootomo): out = [relu](H @ W + b).
// Block: 128 rows x 128 cols, 4 waves each 64x64 (4x4 frags of 16x16x32).
// H staged+split to bf16 hi/lo in LDS per 32-K chunk; W chunks copied from
// the pre-split workspace.  mode 0: write agg in-place; mode 1: d_out.
// ---------------------------------------------------------------------------
__global__ __launch_bounds__(256)
void gemm_k(const float* __restrict__ in_all,
            const short* __restrict__ wsp,
            const float* __restrict__ b_ad, const float* __restrict__ b_da,
            float* __restrict__ out_agg, float* __restrict__ d_out,
            int l, int which, int relu, int mode) {
    __shared__ short sHhi[128][32];
    __shared__ short sHlo[128][32];
    __shared__ short sWhi[128][32];
    __shared__ short sWlo[128][32];

    int z = blockIdx.y, t = z >> 1, et = z & 1;
    int tid = threadIdx.x;
    int mat = (which * 2 + et) * 8 + t * 2 + l;
    const float* in = in_all + (long)z * KN * KH;
    const float* Bp = (et ? b_da : b_ad) + (long)(t * KL + l) * KH;
    int r0 = blockIdx.x * 128;

    int lane = tid & 63, wid = tid >> 6;
    int wr = wid >> 1, wc = wid & 1;
    int lrow = lane & 15, lq = lane >> 4;

    f32x4 acc[4][4];
    #pragma unroll
    for (int i = 0; i < 4; ++i)
        #pragma unroll
        for (int j = 0; j < 4; ++j) acc[i][j] = (f32x4){0.f, 0.f, 0.f, 0.f};

    for (int kc = 0; kc < 4; ++kc) {
        // ---- stage W chunk (copy, already split+transposed) ----
        const short* wh = wsp + ((long)(mat * 2 + 0) * 4 + kc) * 4096;
        const short* wl = wsp + ((long)(mat * 2 + 1) * 4 + kc) * 4096;
        #pragma unroll
        for (int p = 0; p < 2; ++p) {
            int g = p * 256 + tid;          // 512 16B units
            int col = g >> 2, seg = (g & 3) * 8;
            *(short8v*)&sWhi[col][seg] = *(const short8v*)&wh[g * 8];
            *(short8v*)&sWlo[col][seg] = *(const short8v*)&wl[g * 8];
        }
        // ---- stage H chunk with split ----
        #pragma unroll
        for (int p = 0; p < 4; ++p) {
            int g = p * 256 + tid;          // 1024 float4 units
            int row = g >> 3, f4 = g & 7;
            float4 v = make_float4(0.f, 0.f, 0.f, 0.f);
            if (r0 + row < KN)
                v = *(const float4*)&in[(long)(r0 + row) * KH + kc * 32 + f4 * 4];
            short hx = bf16rn(v.x), hy = bf16rn(v.y), hz = bf16rn(v.z), hw = bf16rn(v.w);
            short lx = bf16rn(v.x - bf16tof(hx));
            short ly = bf16rn(v.y - bf16tof(hy));
            short lz = bf16rn(v.z - bf16tof(hz));
            short lw2 = bf16rn(v.w - bf16tof(hw));
            int2 hp, lp;
            hp.x = (int)(((unsigned)(unsigned short)hy << 16) | (unsigned short)hx);
            hp.y = (int)(((unsigned)(unsigned short)hw << 16) | (unsigned short)hz);
            lp.x = (int)(((unsigned)(unsigned short)ly << 16) | (unsigned short)lx);
            lp.y = (int)(((unsigned)(unsigned short)lw2 << 16) | (unsigned short)lz);
            *(int2*)&sHhi[row][f4 * 4] = hp;
            *(int2*)&sHlo[row][f4 * 4] = lp;
        }
        __syncthreads();

        short8v bhi[4], blo[4];
        #pragma unroll
        for (int j = 0; j < 4; ++j) {
            int col = wc * 64 + j * 16 + lrow;
            bhi[j] = *(const short8v*)&sWhi[col][lq * 8];
            blo[j] = *(const short8v*)&sWlo[col][lq * 8];
        }
        #pragma unroll
        for (int i = 0; i < 4; ++i) {
            int row = wr * 64 + i * 16 + lrow;
            short8v ahi = *(const short8v*)&sHhi[row][lq * 8];
            short8v alo = *(const short8v*)&sHlo[row][lq * 8];
            #pragma unroll
            for (int j = 0; j < 4; ++j) {
                acc[i][j] = __builtin_amdgcn_mfma_f32_16x16x32_bf16(ahi, bhi[j], acc[i][j], 0, 0, 0);
                acc[i][j] = __builtin_amdgcn_mfma_f32_16x16x32_bf16(ahi, blo[j], acc[i][j], 0, 0, 0);
                acc[i][j] = __builtin_amdgcn_mfma_f32_16x16x32_bf16(alo, bhi[j], acc[i][j], 0, 0, 0);
            }
        }
        __syncthreads();
    }

    // ---- epilogue: bias + relu + store ----
    #pragma unroll
    for (int j = 0; j < 4; ++j) {
        int col = wc * 64 + j * 16 + lrow;
        float bias = Bp[col];
        #pragma unroll
        for (int i = 0; i < 4; ++i) {
            int rbase = r0 + wr * 64 + i * 16 + lq * 4;
            #pragma unroll
            for (int r = 0; r < 4; ++r) {
                int row = rbase + r;
                if (row >= KN) continue;
                float v = acc[i][j][r] + bias;
                if (relu) v = fmaxf(v, 0.f);
                if (mode == 0) {
                    out_agg[((long)z * KN + row) * KH + col] = v;
                } else {
                    long off = (long)t * KNT * KH + (et == 0 ? (long)KN * KH : 0)
                             + (long)row * KH + col;
                    d_out[off] = v;
                }
            }
        }
    }
}

// ---------------------------------------------------------------------------
extern "C" void kernel_launch(void* const* d_in, const int* in_sizes, int n_in,
                              void* d_out_v, int out_size, void* d_ws, size_t ws_size,
                              hipStream_t stream) {
    const float* x_a    = (const float*)d_in[0];
    const float* x_d    = (const float*)d_in[1];
    const float* ea_ad  = (const float*)d_in[2];
    const float* ea_da  = (const float*)d_in[3];
    const int*   ei_ad  = (const int*)d_in[4];
    const int*   ei_da  = (const int*)d_in[5];
    const float* w1_ad  = (const float*)d_in[6];
    const float* b1_ad  = (const float*)d_in[7];
    const float* w2_ad  = (const float*)d_in[8];
    const float* b2_ad  = (const float*)d_in[9];
    const float* eps_ad = (const float*)d_in[10];
    const float* w1_da  = (const float*)d_in[11];
    const float* b1_da  = (const float*)d_in[12];
    const float* w2_da  = (const float*)d_in[13];
    const float* b2_da  = (const float*)d_in[14];
    const float* eps_da = (const float*)d_in[15];
    float* out = (float*)d_out_v;

    // workspace layout
    float* agg  = (float*)d_ws;                          // 8 * KN * KH floats
    int*   offs = (int*)(agg + (size_t)8 * KN * KH);     // 8 * (KN+1)
    int*   cur  = offs + (size_t)8 * (KN + 1);           // 8 * KN
    int2*  pes  = (int2*)(cur + (size_t)8 * KN);         // 8 * KE int2
    short* wsp  = (short*)(pes + (size_t)8 * KE);        // 32*2*4*4096 shorts = 2MB

    hipMemsetAsync(cur, 0, (size_t)8 * KN * sizeof(int), stream);
    wsplit_k<<<32, 256, 0, stream>>>(w1_ad, w1_da, w2_ad, w2_da, wsp);

    dim3 eg((KE + 255) / 256, 8);
    count_k<<<eg, 256, 0, stream>>>(ei_ad, ei_da, cur);
    scan_k<<<8, 256, 0, stream>>>(cur, offs);
    fill_k<<<eg, 256, 0, stream>>>(ei_ad, ei_da, cur, pes);

    dim3 ag(KN / 16, 8);                 // 1250 x 8, exact
    dim3 gg((KN + 127) / 128, 8);        // 157 x 8

    for (int l = 0; l < KL; ++l) {
        const float* xab; long xats;
        const float* xdb; long xdts;
        if (l == 0) {
            xab = x_a; xats = (long)KN * KH;
            xdb = x_d; xdts = (long)KN * KH;
        } else {
            xab = out;                 xats = (long)KNT * KH;
            xdb = out + (long)KN * KH; xdts = (long)KNT * KH;
        }
        agg_k<<<ag, 256, 0, stream>>>(xab, xats, xdb, xdts,
                                      ea_ad, ea_da,
                                      eps_ad, eps_da, offs, pes, agg, l);
        // mid = relu(H @ w1 + b1), in-place into agg
        gemm_k<<<gg, 256, 0, stream>>>(agg, wsp, b1_ad, b1_da,
                                       agg, out, l, 0, 1, 0);
        // x_new = mid @ w2 + b2 (+relu between layers), into d_out
        gemm_k<<<gg, 256, 0, stream>>>(agg, wsp, b2_ad, b2_da,
                                       agg, out, l, 1, (l == 0) ? 1 : 0, 1);
    }
}

// Round 5
// 647.912 us; speedup vs baseline: 1.1706x; 1.1706x over previous
//
#include <hip/hip_runtime.h>

#define KT 4
#define KN 20000        // NA == ND == 20000
#define KE 100000
#define KH 128
#define KL 2
#define KNT 40000       // NA + ND

typedef __attribute__((ext_vector_type(8))) short short8v;
typedef __attribute__((ext_vector_type(4))) float f32x4;

__device__ __forceinline__ short bf16rn(float x) {
    unsigned u = __float_as_uint(x);
    u = (u + 0x7fffu + ((u >> 16) & 1u)) >> 16;
    return (short)u;
}
__device__ __forceinline__ float bf16tof(short h) {
    return __uint_as_float(((unsigned)(unsigned short)h) << 16);
}

// ---------------------------------------------------------------------------
// CSR build: counts -> scan -> fill (packed (edge, src) pairs).
// ---------------------------------------------------------------------------
__global__ void count_k(const int* __restrict__ ei_ad, const int* __restrict__ ei_da,
                        int* __restrict__ cnt) {
    int e = blockIdx.x * 256 + threadIdx.x;
    int z = blockIdx.y;                 // z = t*2 + et
    if (e >= KE) return;
    int t = z >> 1, et = z & 1;
    const int* ei = et ? ei_da : ei_ad;
    int dst = ei[(t * 2 + 1) * KE + e];
    atomicAdd(&cnt[z * KN + dst], 1);
}

__global__ void scan_k(int* __restrict__ cnt, int* __restrict__ offs) {
    __shared__ int s[256];
    int z = blockIdx.x, tid = threadIdx.x;
    const int CH = (KN + 255) / 256;    // 79
    int n0 = tid * CH;
    int lim = n0 < KN ? min(CH, KN - n0) : 0;
    long base = (long)z * KN + n0;
    int sum = 0;
    for (int i = 0; i < lim; ++i) sum += cnt[base + i];
    s[tid] = sum;
    __syncthreads();
    for (int off = 1; off < 256; off <<= 1) {
        int v = (tid >= off) ? s[tid - off] : 0;
        __syncthreads();
        s[tid] += v;
        __syncthreads();
    }
    int run = s[tid] - sum;             // exclusive prefix
    for (int i = 0; i < lim; ++i) {
        int c = cnt[base + i];
        offs[(long)z * (KN + 1) + n0 + i] = run;
        cnt[base + i] = run;            // becomes fill cursor
        run += c;
    }
    if (tid == 0) offs[(long)z * (KN + 1) + KN] = KE;
}

__global__ void fill_k(const int* __restrict__ ei_ad, const int* __restrict__ ei_da,
                       int* __restrict__ cur, int2* __restrict__ pes) {
    int e = blockIdx.x * 256 + threadIdx.x;
    int z = blockIdx.y;
    if (e >= KE) return;
    int t = z >> 1, et = z & 1;
    const int* ei = et ? ei_da : ei_ad;
    int src = ei[(t * 2 + 0) * KE + e];
    int dst = ei[(t * 2 + 1) * KE + e];
    int pos = atomicAdd(&cur[z * KN + dst], 1);
    pes[(long)z * KE + pos] = make_int2(e, src);
}

// ---------------------------------------------------------------------------
// Aggregation: 32-lane group per node (2 groups/wave, 8 nodes/block), each
// lane owns 4 features (1 float4).  Branchless batch of 8 edges: all 16 row
// gathers issue unconditionally (indices clamped to last edge), contribution
// masked via fmaf(m, relu(x+e), acc).  No control flow -> compiler cannot
// sink/serialize the loads.
// ---------------------------------------------------------------------------
__global__ __launch_bounds__(256)
void agg_k(const float* __restrict__ xa_base, long xa_ts,
           const float* __restrict__ xd_base, long xd_ts,
           const float* __restrict__ ea_ad, const float* __restrict__ ea_da,
           const float* __restrict__ eps_ad, const float* __restrict__ eps_da,
           const int* __restrict__ offs, const int2* __restrict__ pes,
           float* __restrict__ agg, int l) {
    int z = blockIdx.y, t = z >> 1, et = z & 1;
    int li = threadIdx.x & 31;          // lane in 32-lane group
    int node = blockIdx.x * 8 + (threadIdx.x >> 5);   // grid exact: KN/8 blocks

    const float* ea  = (et ? ea_da : ea_ad) + (long)t * KE * KH;
    const float* eps = et ? eps_da : eps_ad;
    const float* src = et ? (xd_base + t * xd_ts) : (xa_base + t * xa_ts);
    const float* dst = et ? (xa_base + t * xa_ts) : (xd_base + t * xd_ts);
    const int2*  pz  = pes + (long)z * KE;

    int beg = offs[(long)z * (KN + 1) + node];
    int end = offs[(long)z * (KN + 1) + node + 1];
    float scale = 1.0f + eps[t * KL + l];

    float4 dv = *(const float4*)(dst + (long)node * KH + li * 4);
    float4 acc = make_float4(0.f, 0.f, 0.f, 0.f);

    if (beg < end) {
        int last = end - 1;
        for (int i = beg; i < end; i += 8) {
            int2 p[8];
            #pragma unroll
            for (int u = 0; u < 8; ++u) p[u] = pz[min(i + u, last)];
            float4 xs[8], es[8];
            #pragma unroll
            for (int u = 0; u < 8; ++u)
                xs[u] = *(const float4*)(src + (long)p[u].y * KH + li * 4);
            #pragma unroll
            for (int u = 0; u < 8; ++u)
                es[u] = *(const float4*)(ea + (long)p[u].x * KH + li * 4);
            #pragma unroll
            for (int u = 0; u < 8; ++u) {
                float m = (i + u < end) ? 1.0f : 0.0f;
                acc.x = fmaf(m, fmaxf(xs[u].x + es[u].x, 0.f), acc.x);
                acc.y = fmaf(m, fmaxf(xs[u].y + es[u].y, 0.f), acc.y);
                acc.z = fmaf(m, fmaxf(xs[u].z + es[u].z, 0.f), acc.z);
                acc.w = fmaf(m, fmaxf(xs[u].w + es[u].w, 0.f), acc.w);
            }
        }
    }

    float4 r;
    r.x = fmaf(scale, dv.x, acc.x);
    r.y = fmaf(scale, dv.y, acc.y);
    r.z = fmaf(scale, dv.z, acc.z);
    r.w = fmaf(scale, dv.w, acc.w);
    *(float4*)(agg + ((long)z * KN + node) * KH + li * 4) = r;
}

// ---------------------------------------------------------------------------
// W pre-split: for each of 32 matrices (4 arrays x T x L), write transposed
// split-bf16 chunks: wsp[((mat*2+h)*4 + kc)*4096 + col*32 + kk],
// W[k][col], k = kc*32+kk.  h=0: hi, h=1: lo.  256 blocks (8 per matrix).
// ---------------------------------------------------------------------------
__global__ __launch_bounds__(256)
void wsplit_k(const float* __restrict__ w1_ad, const float* __restrict__ w1_da,
              const float* __restrict__ w2_ad, const float* __restrict__ w2_da,
              short* __restrict__ wsp) {
    int mat = blockIdx.x >> 3, part = blockIdx.x & 7;   // mat 0..31
    int arr = mat >> 3, rem = mat & 7;   // rem = t*2+l
    const float* src = (arr == 0 ? w1_ad : arr == 1 ? w1_da : arr == 2 ? w2_ad : w2_da)
                       + (long)rem * KH * KH;
    #pragma unroll
    for (int p = 0; p < 8; ++p) {
        int idx = part * 2048 + p * 256 + threadIdx.x;  // 16384 elems total
        int k = idx >> 7, c = idx & 127;
        float v = src[idx];
        short hi = bf16rn(v);
        short lo = bf16rn(v - bf16tof(hi));
        int chunk = k >> 5, kk = k & 31;
        long ohi = ((long)(mat * 2 + 0) * 4 + chunk) * 4096 + c * 32 + kk;
        long olo = ((long)(mat * 2 + 1) * 4 + chunk) * 4096 + c * 32 + kk;
        wsp[ohi] = hi;
        wsp[olo] = lo;
    }
}

// ---------------------------------------------------------------------------
// MFMA GEMM via bf16-split (3-term Ootomo): out = [relu](H @ W + b).
// Block: 128 rows x 128 cols, 4 waves each 64x64 (4x4 frags of 16x16x32).
// LDS rows padded to 40 shorts (80B stride -> 2-way bank access = free).
// MFMA operands SWAPPED (W in A-slot, H in B-slot) so each lane holds 4
// consecutive output columns of one node -> coalesced float4 epilogue.
// ---------------------------------------------------------------------------
#define LP 40           // padded LDS row stride (shorts)

__global__ __launch_bounds__(256)
void gemm_k(const float* __restrict__ in_all,
            const short* __restrict__ wsp,
            const float* __restrict__ b_ad, const float* __restrict__ b_da,
            float* __restrict__ out_agg, float* __restrict__ d_out,
            int l, int which, int relu, int mode) {
    __shared__ short sHhi[128][LP];
    __shared__ short sHlo[128][LP];
    __shared__ short sWhi[128][LP];
    __shared__ short sWlo[128][LP];

    int z = blockIdx.y, t = z >> 1, et = z & 1;
    int tid = threadIdx.x;
    int mat = (which * 2 + et) * 8 + t * 2 + l;
    const float* in = in_all + (long)z * KN * KH;
    const float* Bp = (et ? b_da : b_ad) + (long)(t * KL + l) * KH;
    int r0 = blockIdx.x * 128;

    int lane = tid & 63, wid = tid >> 6;
    int wr = wid >> 1, wc = wid & 1;
    int lrow = lane & 15, lq = lane >> 4;

    f32x4 acc[4][4];
    #pragma unroll
    for (int i = 0; i < 4; ++i)
        #pragma unroll
        for (int j = 0; j < 4; ++j) acc[i][j] = (f32x4){0.f, 0.f, 0.f, 0.f};

    for (int kc = 0; kc < 4; ++kc) {
        // ---- stage W chunk (copy, already split+transposed) ----
        const short* wh = wsp + ((long)(mat * 2 + 0) * 4 + kc) * 4096;
        const short* wl = wsp + ((long)(mat * 2 + 1) * 4 + kc) * 4096;
        #pragma unroll
        for (int p = 0; p < 2; ++p) {
            int g = p * 256 + tid;          // 512 16B units
            int col = g >> 2, seg = (g & 3) * 8;
            *(short8v*)&sWhi[col][seg] = *(const short8v*)&wh[g * 8];
            *(short8v*)&sWlo[col][seg] = *(const short8v*)&wl[g * 8];
        }
        // ---- stage H chunk with fp32 -> bf16 hi/lo split ----
        #pragma unroll
        for (int p = 0; p < 4; ++p) {
            int g = p * 256 + tid;          // 1024 float4 units
            int row = g >> 3, f4 = g & 7;
            float4 v = make_float4(0.f, 0.f, 0.f, 0.f);
            if (r0 + row < KN)
                v = *(const float4*)&in[(long)(r0 + row) * KH + kc * 32 + f4 * 4];
            short hx = bf16rn(v.x), hy = bf16rn(v.y), hz = bf16rn(v.z), hw = bf16rn(v.w);
            short lx = bf16rn(v.x - bf16tof(hx));
            short ly = bf16rn(v.y - bf16tof(hy));
            short lz = bf16rn(v.z - bf16tof(hz));
            short lw2 = bf16rn(v.w - bf16tof(hw));
            int2 hp, lp;
            hp.x = (int)(((unsigned)(unsigned short)hy << 16) | (unsigned short)hx);
            hp.y = (int)(((unsigned)(unsigned short)hw << 16) | (unsigned short)hz);
            lp.x = (int)(((unsigned)(unsigned short)ly << 16) | (unsigned short)lx);
            lp.y = (int)(((unsigned)(unsigned short)lw2 << 16) | (unsigned short)lz);
            *(int2*)&sHhi[row][f4 * 4] = hp;
            *(int2*)&sHlo[row][f4 * 4] = lp;
        }
        __syncthreads();

        short8v bhi[4], blo[4];
        #pragma unroll
        for (int j = 0; j < 4; ++j) {
            int col = wc * 64 + j * 16 + lrow;
            bhi[j] = *(const short8v*)&sWhi[col][lq * 8];
            blo[j] = *(const short8v*)&sWlo[col][lq * 8];
        }
        #pragma unroll
        for (int i = 0; i < 4; ++i) {
            int row = wr * 64 + i * 16 + lrow;
            short8v ahi = *(const short8v*)&sHhi[row][lq * 8];
            short8v alo = *(const short8v*)&sHlo[row][lq * 8];
            #pragma unroll
            for (int j = 0; j < 4; ++j) {
                // swapped: W frag in A-slot, H frag in B-slot -> D[c][node]
                acc[i][j] = __builtin_amdgcn_mfma_f32_16x16x32_bf16(bhi[j], ahi, acc[i][j], 0, 0, 0);
                acc[i][j] = __builtin_amdgcn_mfma_f32_16x16x32_bf16(blo[j], ahi, acc[i][j], 0, 0, 0);
                acc[i][j] = __builtin_amdgcn_mfma_f32_16x16x32_bf16(bhi[j], alo, acc[i][j], 0, 0, 0);
            }
        }
        __syncthreads();
    }

    // ---- epilogue: lane holds cols (wc*64+j*16+lq*4 .. +3) of node
    //      (r0+wr*64+i*16+lrow) -> coalesced float4 stores ----
    #pragma unroll
    for (int i = 0; i < 4; ++i) {
        int node = r0 + wr * 64 + i * 16 + lrow;
        if (node >= KN) continue;
        #pragma unroll
        for (int j = 0; j < 4; ++j) {
            int col = wc * 64 + j * 16 + lq * 4;
            float4 b4 = *(const float4*)&Bp[col];
            f32x4 a = acc[i][j];
            float4 v;
            v.x = a[0] + b4.x; v.y = a[1] + b4.y;
            v.z = a[2] + b4.z; v.w = a[3] + b4.w;
            if (relu) {
                v.x = fmaxf(v.x, 0.f); v.y = fmaxf(v.y, 0.f);
                v.z = fmaxf(v.z, 0.f); v.w = fmaxf(v.w, 0.f);
            }
            if (mode == 0) {
                *(float4*)&out_agg[((long)z * KN + node) * KH + col] = v;
            } else {
                long off = (long)t * KNT * KH + (et == 0 ? (long)KN * KH : 0)
                         + (long)node * KH + col;
                *(float4*)&d_out[off] = v;
            }
        }
    }
}

// ---------------------------------------------------------------------------
extern "C" void kernel_launch(void* const* d_in, const int* in_sizes, int n_in,
                              void* d_out_v, int out_size, void* d_ws, size_t ws_size,
                              hipStream_t stream) {
    const float* x_a    = (const float*)d_in[0];
    const float* x_d    = (const float*)d_in[1];
    const float* ea_ad  = (const float*)d_in[2];
    const float* ea_da  = (const float*)d_in[3];
    const int*   ei_ad  = (const int*)d_in[4];
    const int*   ei_da  = (const int*)d_in[5];
    const float* w1_ad  = (const float*)d_in[6];
    const float* b1_ad  = (const float*)d_in[7];
    const float* w2_ad  = (const float*)d_in[8];
    const float* b2_ad  = (const float*)d_in[9];
    const float* eps_ad = (const float*)d_in[10];
    const float* w1_da  = (const float*)d_in[11];
    const float* b1_da  = (const float*)d_in[12];
    const float* w2_da  = (const float*)d_in[13];
    const float* b2_da  = (const float*)d_in[14];
    const float* eps_da = (const float*)d_in[15];
    float* out = (float*)d_out_v;

    // workspace layout
    float* agg  = (float*)d_ws;                          // 8 * KN * KH floats
    int*   offs = (int*)(agg + (size_t)8 * KN * KH);     // 8 * (KN+1)
    int*   cur  = offs + (size_t)8 * (KN + 1);           // 8 * KN
    int2*  pes  = (int2*)(cur + (size_t)8 * KN);         // 8 * KE int2
    short* wsp  = (short*)(pes + (size_t)8 * KE);        // 32*2*4*4096 shorts = 2MB

    hipMemsetAsync(cur, 0, (size_t)8 * KN * sizeof(int), stream);
    wsplit_k<<<256, 256, 0, stream>>>(w1_ad, w1_da, w2_ad, w2_da, wsp);

    dim3 eg((KE + 255) / 256, 8);
    count_k<<<eg, 256, 0, stream>>>(ei_ad, ei_da, cur);
    scan_k<<<8, 256, 0, stream>>>(cur, offs);
    fill_k<<<eg, 256, 0, stream>>>(ei_ad, ei_da, cur, pes);

    dim3 ag(KN / 8, 8);                  // 2500 x 8, exact
    dim3 gg((KN + 127) / 128, 8);        // 157 x 8

    for (int l = 0; l < KL; ++l) {
        const float* xab; long xats;
        const float* xdb; long xdts;
        if (l == 0) {
            xab = x_a; xats = (long)KN * KH;
            xdb = x_d; xdts = (long)KN * KH;
        } else {
            xab = out;                 xats = (long)KNT * KH;
            xdb = out + (long)KN * KH; xdts = (long)KNT * KH;
        }
        agg_k<<<ag, 256, 0, stream>>>(xab, xats, xdb, xdts,
                                      ea_ad, ea_da,
                                      eps_ad, eps_da, offs, pes, agg, l);
        // mid = relu(H @ w1 + b1), in-place into agg
        gemm_k<<<gg, 256, 0, stream>>>(agg, wsp, b1_ad, b1_da,
                                       agg, out, l, 0, 1, 0);
        // x_new = mid @ w2 + b2 (+relu between layers), into d_out
        gemm_k<<<gg, 256, 0, stream>>>(agg, wsp, b2_ad, b2_da,
                                       agg, out, l, 1, (l == 0) ? 1 : 0, 1);
    }
}

// Round 6
// 639.821 us; speedup vs baseline: 1.1854x; 1.0126x over previous
//
#include <hip/hip_runtime.h>

#define KT 4
#define KN 20000        // NA == ND == 20000
#define KE 100000
#define KH 128
#define KL 2
#define KNT 40000       // NA + ND

typedef __attribute__((ext_vector_type(8))) short short8v;
typedef __attribute__((ext_vector_type(4))) float f32x4;

__device__ __forceinline__ short bf16rn(float x) {
    unsigned u = __float_as_uint(x);
    u = (u + 0x7fffu + ((u >> 16) & 1u)) >> 16;
    return (short)u;
}
__device__ __forceinline__ float bf16tof(short h) {
    return __uint_as_float(((unsigned)(unsigned short)h) << 16);
}

// ---------------------------------------------------------------------------
// CSR build: counts -> scan -> fill (packed (edge, src) pairs).
// ---------------------------------------------------------------------------
__global__ void count_k(const int* __restrict__ ei_ad, const int* __restrict__ ei_da,
                        int* __restrict__ cnt) {
    int e = blockIdx.x * 256 + threadIdx.x;
    int z = blockIdx.y;                 // z = t*2 + et
    if (e >= KE) return;
    int t = z >> 1, et = z & 1;
    const int* ei = et ? ei_da : ei_ad;
    int dst = ei[(t * 2 + 1) * KE + e];
    atomicAdd(&cnt[z * KN + dst], 1);
}

__global__ void scan_k(int* __restrict__ cnt, int* __restrict__ offs) {
    __shared__ int s[256];
    int z = blockIdx.x, tid = threadIdx.x;
    const int CH = (KN + 255) / 256;    // 79
    int n0 = tid * CH;
    int lim = n0 < KN ? min(CH, KN - n0) : 0;
    long base = (long)z * KN + n0;
    int sum = 0;
    for (int i = 0; i < lim; ++i) sum += cnt[base + i];
    s[tid] = sum;
    __syncthreads();
    for (int off = 1; off < 256; off <<= 1) {
        int v = (tid >= off) ? s[tid - off] : 0;
        __syncthreads();
        s[tid] += v;
        __syncthreads();
    }
    int run = s[tid] - sum;             // exclusive prefix
    for (int i = 0; i < lim; ++i) {
        int c = cnt[base + i];
        offs[(long)z * (KN + 1) + n0 + i] = run;
        cnt[base + i] = run;            // becomes fill cursor
        run += c;
    }
    if (tid == 0) offs[(long)z * (KN + 1) + KN] = KE;
}

__global__ void fill_k(const int* __restrict__ ei_ad, const int* __restrict__ ei_da,
                       int* __restrict__ cur, int2* __restrict__ pes) {
    int e = blockIdx.x * 256 + threadIdx.x;
    int z = blockIdx.y;
    if (e >= KE) return;
    int t = z >> 1, et = z & 1;
    const int* ei = et ? ei_da : ei_ad;
    int src = ei[(t * 2 + 0) * KE + e];
    int dst = ei[(t * 2 + 1) * KE + e];
    int pos = atomicAdd(&cur[z * KN + dst], 1);
    pes[(long)z * KE + pos] = make_int2(e, src);
}

// ---------------------------------------------------------------------------
// Aggregation: 32-lane group per node, batch of 8 edges, branchless.
// sched_barrier(0) fences pin the schedule: 8 pes loads | 16 row gathers |
// accumulate.  All 16 float4 gathers stay in flight together (one vmcnt
// drain per batch) instead of being sunk to their uses by the scheduler.
// ---------------------------------------------------------------------------
__global__ __launch_bounds__(256)
void agg_k(const float* __restrict__ xa_base, long xa_ts,
           const float* __restrict__ xd_base, long xd_ts,
           const float* __restrict__ ea_ad, const float* __restrict__ ea_da,
           const float* __restrict__ eps_ad, const float* __restrict__ eps_da,
           const int* __restrict__ offs, const int2* __restrict__ pes,
           float* __restrict__ agg, int l) {
    int z = blockIdx.y, t = z >> 1, et = z & 1;
    int li = threadIdx.x & 31;          // lane in 32-lane group
    int node = blockIdx.x * 8 + (threadIdx.x >> 5);   // grid exact: KN/8 blocks

    const float* ea  = (et ? ea_da : ea_ad) + (long)t * KE * KH;
    const float* eps = et ? eps_da : eps_ad;
    const float* src = et ? (xd_base + t * xd_ts) : (xa_base + t * xa_ts);
    const float* dst = et ? (xa_base + t * xa_ts) : (xd_base + t * xd_ts);
    const int2*  pz  = pes + (long)z * KE;

    int beg = offs[(long)z * (KN + 1) + node];
    int end = offs[(long)z * (KN + 1) + node + 1];
    float scale = 1.0f + eps[t * KL + l];

    float4 dv = *(const float4*)(dst + (long)node * KH + li * 4);
    float4 acc = make_float4(0.f, 0.f, 0.f, 0.f);

    if (beg < end) {
        int last = end - 1;
        for (int i = beg; i < end; i += 8) {
            int2 p[8];
            #pragma unroll
            for (int u = 0; u < 8; ++u) p[u] = pz[min(i + u, last)];
            float4 xs[8], es[8];
            #pragma unroll
            for (int u = 0; u < 8; ++u)
                xs[u] = *(const float4*)(src + (long)p[u].y * KH + li * 4);
            #pragma unroll
            for (int u = 0; u < 8; ++u)
                es[u] = *(const float4*)(ea + (long)p[u].x * KH + li * 4);
            // pin: all 16 gathers issued before any use
            __builtin_amdgcn_sched_barrier(0);
            #pragma unroll
            for (int u = 0; u < 8; ++u) {
                float m = (i + u < end) ? 1.0f : 0.0f;
                acc.x = fmaf(m, fmaxf(xs[u].x + es[u].x, 0.f), acc.x);
                acc.y = fmaf(m, fmaxf(xs[u].y + es[u].y, 0.f), acc.y);
                acc.z = fmaf(m, fmaxf(xs[u].z + es[u].z, 0.f), acc.z);
                acc.w = fmaf(m, fmaxf(xs[u].w + es[u].w, 0.f), acc.w);
            }
            __builtin_amdgcn_sched_barrier(0);
        }
    }

    float4 r;
    r.x = fmaf(scale, dv.x, acc.x);
    r.y = fmaf(scale, dv.y, acc.y);
    r.z = fmaf(scale, dv.z, acc.z);
    r.w = fmaf(scale, dv.w, acc.w);
    *(float4*)(agg + ((long)z * KN + node) * KH + li * 4) = r;
}

// ---------------------------------------------------------------------------
// W pre-split: for each of 32 matrices (4 arrays x T x L), write transposed
// split-bf16 chunks: wsp[((mat*2+h)*4 + kc)*4096 + col*32 + kk],
// W[k][col], k = kc*32+kk.  h=0: hi, h=1: lo.  256 blocks (8 per matrix).
// ---------------------------------------------------------------------------
__global__ __launch_bounds__(256)
void wsplit_k(const float* __restrict__ w1_ad, const float* __restrict__ w1_da,
              const float* __restrict__ w2_ad, const float* __restrict__ w2_da,
              short* __restrict__ wsp) {
    int mat = blockIdx.x >> 3, part = blockIdx.x & 7;   // mat 0..31
    int arr = mat >> 3, rem = mat & 7;   // rem = t*2+l
    const float* src = (arr == 0 ? w1_ad : arr == 1 ? w1_da : arr == 2 ? w2_ad : w2_da)
                       + (long)rem * KH * KH;
    #pragma unroll
    for (int p = 0; p < 8; ++p) {
        int idx = part * 2048 + p * 256 + threadIdx.x;  // 16384 elems total
        int k = idx >> 7, c = idx & 127;
        float v = src[idx];
        short hi = bf16rn(v);
        short lo = bf16rn(v - bf16tof(hi));
        int chunk = k >> 5, kk = k & 31;
        long ohi = ((long)(mat * 2 + 0) * 4 + chunk) * 4096 + c * 32 + kk;
        long olo = ((long)(mat * 2 + 1) * 4 + chunk) * 4096 + c * 32 + kk;
        wsp[ohi] = hi;
        wsp[olo] = lo;
    }
}

// ---------------------------------------------------------------------------
// MFMA GEMM via bf16-split (3-term Ootomo): out = [relu](H @ W + b).
// Block: 128 rows x 128 cols, 4 waves each 64x64 (4x4 frags of 16x16x32).
// LDS rows padded to 40 shorts (80B stride -> 2-way bank access = free).
// MFMA operands SWAPPED (W in A-slot, H in B-slot) so each lane holds 4
// consecutive output columns of one node -> coalesced float4 epilogue.
// ---------------------------------------------------------------------------
#define LP 40           // padded LDS row stride (shorts)

__global__ __launch_bounds__(256)
void gemm_k(const float* __restrict__ in_all,
            const short* __restrict__ wsp,
            const float* __restrict__ b_ad, const float* __restrict__ b_da,
            float* __restrict__ out_agg, float* __restrict__ d_out,
            int l, int which, int relu, int mode) {
    __shared__ short sHhi[128][LP];
    __shared__ short sHlo[128][LP];
    __shared__ short sWhi[128][LP];
    __shared__ short sWlo[128][LP];

    int z = blockIdx.y, t = z >> 1, et = z & 1;
    int tid = threadIdx.x;
    int mat = (which * 2 + et) * 8 + t * 2 + l;
    const float* in = in_all + (long)z * KN * KH;
    const float* Bp = (et ? b_da : b_ad) + (long)(t * KL + l) * KH;
    int r0 = blockIdx.x * 128;

    int lane = tid & 63, wid = tid >> 6;
    int wr = wid >> 1, wc = wid & 1;
    int lrow = lane & 15, lq = lane >> 4;

    f32x4 acc[4][4];
    #pragma unroll
    for (int i = 0; i < 4; ++i)
        #pragma unroll
        for (int j = 0; j < 4; ++j) acc[i][j] = (f32x4){0.f, 0.f, 0.f, 0.f};

    for (int kc = 0; kc < 4; ++kc) {
        // ---- stage W chunk (copy, already split+transposed) ----
        const short* wh = wsp + ((long)(mat * 2 + 0) * 4 + kc) * 4096;
        const short* wl = wsp + ((long)(mat * 2 + 1) * 4 + kc) * 4096;
        #pragma unroll
        for (int p = 0; p < 2; ++p) {
            int g = p * 256 + tid;          // 512 16B units
            int col = g >> 2, seg = (g & 3) * 8;
            *(short8v*)&sWhi[col][seg] = *(const short8v*)&wh[g * 8];
            *(short8v*)&sWlo[col][seg] = *(const short8v*)&wl[g * 8];
        }
        // ---- stage H chunk with fp32 -> bf16 hi/lo split ----
        #pragma unroll
        for (int p = 0; p < 4; ++p) {
            int g = p * 256 + tid;          // 1024 float4 units
            int row = g >> 3, f4 = g & 7;
            float4 v = make_float4(0.f, 0.f, 0.f, 0.f);
            if (r0 + row < KN)
                v = *(const float4*)&in[(long)(r0 + row) * KH + kc * 32 + f4 * 4];
            short hx = bf16rn(v.x), hy = bf16rn(v.y), hz = bf16rn(v.z), hw = bf16rn(v.w);
            short lx = bf16rn(v.x - bf16tof(hx));
            short ly = bf16rn(v.y - bf16tof(hy));
            short lz = bf16rn(v.z - bf16tof(hz));
            short lw2 = bf16rn(v.w - bf16tof(hw));
            int2 hp, lp;
            hp.x = (int)(((unsigned)(unsigned short)hy << 16) | (unsigned short)hx);
            hp.y = (int)(((unsigned)(unsigned short)hw << 16) | (unsigned short)hz);
            lp.x = (int)(((unsigned)(unsigned short)ly << 16) | (unsigned short)lx);
            lp.y = (int)(((unsigned)(unsigned short)lw2 << 16) | (unsigned short)lz);
            *(int2*)&sHhi[row][f4 * 4] = hp;
            *(int2*)&sHlo[row][f4 * 4] = lp;
        }
        __syncthreads();

        short8v bhi[4], blo[4];
        #pragma unroll
        for (int j = 0; j < 4; ++j) {
            int col = wc * 64 + j * 16 + lrow;
            bhi[j] = *(const short8v*)&sWhi[col][lq * 8];
            blo[j] = *(const short8v*)&sWlo[col][lq * 8];
        }
        #pragma unroll
        for (int i = 0; i < 4; ++i) {
            int row = wr * 64 + i * 16 + lrow;
            short8v ahi = *(const short8v*)&sHhi[row][lq * 8];
            short8v alo = *(const short8v*)&sHlo[row][lq * 8];
            #pragma unroll
            for (int j = 0; j < 4; ++j) {
                // swapped: W frag in A-slot, H frag in B-slot -> D[c][node]
                acc[i][j] = __builtin_amdgcn_mfma_f32_16x16x32_bf16(bhi[j], ahi, acc[i][j], 0, 0, 0);
                acc[i][j] = __builtin_amdgcn_mfma_f32_16x16x32_bf16(blo[j], ahi, acc[i][j], 0, 0, 0);
                acc[i][j] = __builtin_amdgcn_mfma_f32_16x16x32_bf16(bhi[j], alo, acc[i][j], 0, 0, 0);
            }
        }
        __syncthreads();
    }

    // ---- epilogue: lane holds cols (wc*64+j*16+lq*4 .. +3) of node
    //      (r0+wr*64+i*16+lrow) -> coalesced float4 stores ----
    #pragma unroll
    for (int i = 0; i < 4; ++i) {
        int node = r0 + wr * 64 + i * 16 + lrow;
        if (node >= KN) continue;
        #pragma unroll
        for (int j = 0; j < 4; ++j) {
            int col = wc * 64 + j * 16 + lq * 4;
            float4 b4 = *(const float4*)&Bp[col];
            f32x4 a = acc[i][j];
            float4 v;
            v.x = a[0] + b4.x; v.y = a[1] + b4.y;
            v.z = a[2] + b4.z; v.w = a[3] + b4.w;
            if (relu) {
                v.x = fmaxf(v.x, 0.f); v.y = fmaxf(v.y, 0.f);
                v.z = fmaxf(v.z, 0.f); v.w = fmaxf(v.w, 0.f);
            }
            if (mode == 0) {
                *(float4*)&out_agg[((long)z * KN + node) * KH + col] = v;
            } else {
                long off = (long)t * KNT * KH + (et == 0 ? (long)KN * KH : 0)
                         + (long)node * KH + col;
                *(float4*)&d_out[off] = v;
            }
        }
    }
}

// ---------------------------------------------------------------------------
extern "C" void kernel_launch(void* const* d_in, const int* in_sizes, int n_in,
                              void* d_out_v, int out_size, void* d_ws, size_t ws_size,
                              hipStream_t stream) {
    const float* x_a    = (const float*)d_in[0];
    const float* x_d    = (const float*)d_in[1];
    const float* ea_ad  = (const float*)d_in[2];
    const float* ea_da  = (const float*)d_in[3];
    const int*   ei_ad  = (const int*)d_in[4];
    const int*   ei_da  = (const int*)d_in[5];
    const float* w1_ad  = (const float*)d_in[6];
    const float* b1_ad  = (const float*)d_in[7];
    const float* w2_ad  = (const float*)d_in[8];
    const float* b2_ad  = (const float*)d_in[9];
    const float* eps_ad = (const float*)d_in[10];
    const float* w1_da  = (const float*)d_in[11];
    const float* b1_da  = (const float*)d_in[12];
    const float* w2_da  = (const float*)d_in[13];
    const float* b2_da  = (const float*)d_in[14];
    const float* eps_da = (const float*)d_in[15];
    float* out = (float*)d_out_v;

    // workspace layout
    float* agg  = (float*)d_ws;                          // 8 * KN * KH floats
    int*   offs = (int*)(agg + (size_t)8 * KN * KH);     // 8 * (KN+1)
    int*   cur  = offs + (size_t)8 * (KN + 1);           // 8 * KN
    int2*  pes  = (int2*)(cur + (size_t)8 * KN);         // 8 * KE int2
    short* wsp  = (short*)(pes + (size_t)8 * KE);        // 32*2*4*4096 shorts = 2MB

    hipMemsetAsync(cur, 0, (size_t)8 * KN * sizeof(int), stream);
    wsplit_k<<<256, 256, 0, stream>>>(w1_ad, w1_da, w2_ad, w2_da, wsp);

    dim3 eg((KE + 255) / 256, 8);
    count_k<<<eg, 256, 0, stream>>>(ei_ad, ei_da, cur);
    scan_k<<<8, 256, 0, stream>>>(cur, offs);
    fill_k<<<eg, 256, 0, stream>>>(ei_ad, ei_da, cur, pes);

    dim3 ag(KN / 8, 8);                  // 2500 x 8, exact
    dim3 gg((KN + 127) / 128, 8);        // 157 x 8

    for (int l = 0; l < KL; ++l) {
        const float* xab; long xats;
        const float* xdb; long xdts;
        if (l == 0) {
            xab = x_a; xats = (long)KN * KH;
            xdb = x_d; xdts = (long)KN * KH;
        } else {
            xab = out;                 xats = (long)KNT * KH;
            xdb = out + (long)KN * KH; xdts = (long)KNT * KH;
        }
        agg_k<<<ag, 256, 0, stream>>>(xab, xats, xdb, xdts,
                                      ea_ad, ea_da,
                                      eps_ad, eps_da, offs, pes, agg, l);
        // mid = relu(H @ w1 + b1), in-place into agg
        gemm_k<<<gg, 256, 0, stream>>>(agg, wsp, b1_ad, b1_da,
                                       agg, out, l, 0, 1, 0);
        // x_new = mid @ w2 + b2 (+relu between layers), into d_out
        gemm_k<<<gg, 256, 0, stream>>>(agg, wsp, b2_ad, b2_da,
                                       agg, out, l, 1, (l == 0) ? 1 : 0, 1);
    }
}

// Round 7
// 635.968 us; speedup vs baseline: 1.1925x; 1.0061x over previous
//
#include <hip/hip_runtime.h>

#define KT 4
#define KN 20000        // NA == ND == 20000
#define KE 100000
#define KH 128
#define KL 2
#define KNT 40000       // NA + ND

typedef __attribute__((ext_vector_type(8))) short short8v;
typedef __attribute__((ext_vector_type(4))) float f32x4;

__device__ __forceinline__ short bf16rn(float x) {
    unsigned u = __float_as_uint(x);
    u = (u + 0x7fffu + ((u >> 16) & 1u)) >> 16;
    return (short)u;
}
__device__ __forceinline__ float bf16tof(short h) {
    return __uint_as_float(((unsigned)(unsigned short)h) << 16);
}

// ---------------------------------------------------------------------------
// CSR build: counts -> scan -> fill (packed (edge, src) pairs).
// ---------------------------------------------------------------------------
__global__ void count_k(const int* __restrict__ ei_ad, const int* __restrict__ ei_da,
                        int* __restrict__ cnt) {
    int e = blockIdx.x * 256 + threadIdx.x;
    int z = blockIdx.y;                 // z = t*2 + et
    if (e >= KE) return;
    int t = z >> 1, et = z & 1;
    const int* ei = et ? ei_da : ei_ad;
    int dst = ei[(t * 2 + 1) * KE + e];
    atomicAdd(&cnt[z * KN + dst], 1);
}

__global__ void scan_k(int* __restrict__ cnt, int* __restrict__ offs) {
    __shared__ int s[256];
    int z = blockIdx.x, tid = threadIdx.x;
    const int CH = (KN + 255) / 256;    // 79
    int n0 = tid * CH;
    int lim = n0 < KN ? min(CH, KN - n0) : 0;
    long base = (long)z * KN + n0;
    int sum = 0;
    for (int i = 0; i < lim; ++i) sum += cnt[base + i];
    s[tid] = sum;
    __syncthreads();
    for (int off = 1; off < 256; off <<= 1) {
        int v = (tid >= off) ? s[tid - off] : 0;
        __syncthreads();
        s[tid] += v;
        __syncthreads();
    }
    int run = s[tid] - sum;             // exclusive prefix
    for (int i = 0; i < lim; ++i) {
        int c = cnt[base + i];
        offs[(long)z * (KN + 1) + n0 + i] = run;
        cnt[base + i] = run;            // becomes fill cursor
        run += c;
    }
    if (tid == 0) offs[(long)z * (KN + 1) + KN] = KE;
}

__global__ void fill_k(const int* __restrict__ ei_ad, const int* __restrict__ ei_da,
                       int* __restrict__ cur, int2* __restrict__ pes) {
    int e = blockIdx.x * 256 + threadIdx.x;
    int z = blockIdx.y;
    if (e >= KE) return;
    int t = z >> 1, et = z & 1;
    const int* ei = et ? ei_da : ei_ad;
    int src = ei[(t * 2 + 0) * KE + e];
    int dst = ei[(t * 2 + 1) * KE + e];
    int pos = atomicAdd(&cur[z * KN + dst], 1);
    pes[(long)z * KE + pos] = make_int2(e, src);
}

// ---------------------------------------------------------------------------
// Aggregation: 32-lane group per node, batch of 8 edges.  The 16 row gathers
// are issued as asm volatile global_load_dwordx4 (cannot be reordered or
// sunk; all 16 dest quads stay live) followed by ONE s_waitcnt vmcnt(0) +
// sched_barrier -> one latency drain per batch instead of 16.
// ---------------------------------------------------------------------------
__global__ __launch_bounds__(256)
void agg_k(const float* __restrict__ xa_base, long xa_ts,
           const float* __restrict__ xd_base, long xd_ts,
           const float* __restrict__ ea_ad, const float* __restrict__ ea_da,
           const float* __restrict__ eps_ad, const float* __restrict__ eps_da,
           const int* __restrict__ offs, const int2* __restrict__ pes,
           float* __restrict__ agg, int l) {
    int z = blockIdx.y, t = z >> 1, et = z & 1;
    int li = threadIdx.x & 31;          // lane in 32-lane group
    int node = blockIdx.x * 8 + (threadIdx.x >> 5);   // grid exact: KN/8 blocks

    const float* ea  = (et ? ea_da : ea_ad) + (long)t * KE * KH;
    const float* eps = et ? eps_da : eps_ad;
    const float* src = et ? (xd_base + t * xd_ts) : (xa_base + t * xa_ts);
    const float* dst = et ? (xa_base + t * xa_ts) : (xd_base + t * xd_ts);
    const int2*  pz  = pes + (long)z * KE;

    int beg = offs[(long)z * (KN + 1) + node];
    int end = offs[(long)z * (KN + 1) + node + 1];
    float scale = 1.0f + eps[t * KL + l];

    float4 dv = *(const float4*)(dst + (long)node * KH + li * 4);
    float acx = 0.f, acy = 0.f, acz = 0.f, acw = 0.f;

    if (beg < end) {
        int last = end - 1;
        for (int i = beg; i < end; i += 8) {
            int2 p[8];
            #pragma unroll
            for (int u = 0; u < 8; ++u) p[u] = pz[min(i + u, last)];
            f32x4 xs[8], es[8];
            #pragma unroll
            for (int u = 0; u < 8; ++u) {
                const float* ax = src + (long)p[u].y * KH + li * 4;
                const float* ae = ea  + (long)p[u].x * KH + li * 4;
                asm volatile("global_load_dwordx4 %0, %1, off"
                             : "=v"(xs[u]) : "v"(ax));
                asm volatile("global_load_dwordx4 %0, %1, off"
                             : "=v"(es[u]) : "v"(ae));
            }
            asm volatile("s_waitcnt vmcnt(0)" ::: "memory");
            __builtin_amdgcn_sched_barrier(0);
            #pragma unroll
            for (int u = 0; u < 8; ++u) {
                float m = (i + u < end) ? 1.0f : 0.0f;
                acx = fmaf(m, fmaxf(xs[u][0] + es[u][0], 0.f), acx);
                acy = fmaf(m, fmaxf(xs[u][1] + es[u][1], 0.f), acy);
                acz = fmaf(m, fmaxf(xs[u][2] + es[u][2], 0.f), acz);
                acw = fmaf(m, fmaxf(xs[u][3] + es[u][3], 0.f), acw);
            }
        }
    }

    float4 r;
    r.x = fmaf(scale, dv.x, acx);
    r.y = fmaf(scale, dv.y, acy);
    r.z = fmaf(scale, dv.z, acz);
    r.w = fmaf(scale, dv.w, acw);
    *(float4*)(agg + ((long)z * KN + node) * KH + li * 4) = r;
}

// ---------------------------------------------------------------------------
// W pre-split: for each of 32 matrices (4 arrays x T x L), write transposed
// split-bf16 chunks: wsp[((mat*2+h)*4 + kc)*4096 + col*32 + kk],
// W[k][col], k = kc*32+kk.  h=0: hi, h=1: lo.  256 blocks (8 per matrix).
// ---------------------------------------------------------------------------
__global__ __launch_bounds__(256)
void wsplit_k(const float* __restrict__ w1_ad, const float* __restrict__ w1_da,
              const float* __restrict__ w2_ad, const float* __restrict__ w2_da,
              short* __restrict__ wsp) {
    int mat = blockIdx.x >> 3, part = blockIdx.x & 7;   // mat 0..31
    int arr = mat >> 3, rem = mat & 7;   // rem = t*2+l
    const float* src = (arr == 0 ? w1_ad : arr == 1 ? w1_da : arr == 2 ? w2_ad : w2_da)
                       + (long)rem * KH * KH;
    #pragma unroll
    for (int p = 0; p < 8; ++p) {
        int idx = part * 2048 + p * 256 + threadIdx.x;  // 16384 elems total
        int k = idx >> 7, c = idx & 127;
        float v = src[idx];
        short hi = bf16rn(v);
        short lo = bf16rn(v - bf16tof(hi));
        int chunk = k >> 5, kk = k & 31;
        long ohi = ((long)(mat * 2 + 0) * 4 + chunk) * 4096 + c * 32 + kk;
        long olo = ((long)(mat * 2 + 1) * 4 + chunk) * 4096 + c * 32 + kk;
        wsp[ohi] = hi;
        wsp[olo] = lo;
    }
}

// ---------------------------------------------------------------------------
// MFMA GEMM via bf16-split (3-term Ootomo): out = [relu](H @ W + b).
// Block: 128 rows x 128 cols, 4 waves each 64x64 (4x4 frags of 16x16x32).
// LDS rows padded to 40 shorts (80B stride -> 2-way bank access = free).
// MFMA operands SWAPPED (W in A-slot, H in B-slot) so each lane holds 4
// consecutive output columns of one node -> coalesced float4 epilogue.
// ---------------------------------------------------------------------------
#define LP 40           // padded LDS row stride (shorts)

__global__ __launch_bounds__(256)
void gemm_k(const float* __restrict__ in_all,
            const short* __restrict__ wsp,
            const float* __restrict__ b_ad, const float* __restrict__ b_da,
            float* __restrict__ out_agg, float* __restrict__ d_out,
            int l, int which, int relu, int mode) {
    __shared__ short sHhi[128][LP];
    __shared__ short sHlo[128][LP];
    __shared__ short sWhi[128][LP];
    __shared__ short sWlo[128][LP];

    int z = blockIdx.y, t = z >> 1, et = z & 1;
    int tid = threadIdx.x;
    int mat = (which * 2 + et) * 8 + t * 2 + l;
    const float* in = in_all + (long)z * KN * KH;
    const float* Bp = (et ? b_da : b_ad) + (long)(t * KL + l) * KH;
    int r0 = blockIdx.x * 128;

    int lane = tid & 63, wid = tid >> 6;
    int wr = wid >> 1, wc = wid & 1;
    int lrow = lane & 15, lq = lane >> 4;

    f32x4 acc[4][4];
    #pragma unroll
    for (int i = 0; i < 4; ++i)
        #pragma unroll
        for (int j = 0; j < 4; ++j) acc[i][j] = (f32x4){0.f, 0.f, 0.f, 0.f};

    for (int kc = 0; kc < 4; ++kc) {
        // ---- stage W chunk (copy, already split+transposed) ----
        const short* wh = wsp + ((long)(mat * 2 + 0) * 4 + kc) * 4096;
        const short* wl = wsp + ((long)(mat * 2 + 1) * 4 + kc) * 4096;
        #pragma unroll
        for (int p = 0; p < 2; ++p) {
            int g = p * 256 + tid;          // 512 16B units
            int col = g >> 2, seg = (g & 3) * 8;
            *(short8v*)&sWhi[col][seg] = *(const short8v*)&wh[g * 8];
            *(short8v*)&sWlo[col][seg] = *(const short8v*)&wl[g * 8];
        }
        // ---- stage H chunk with fp32 -> bf16 hi/lo split ----
        #pragma unroll
        for (int p = 0; p < 4; ++p) {
            int g = p * 256 + tid;          // 1024 float4 units
            int row = g >> 3, f4 = g & 7;
            float4 v = make_float4(0.f, 0.f, 0.f, 0.f);
            if (r0 + row < KN)
                v = *(const float4*)&in[(long)(r0 + row) * KH + kc * 32 + f4 * 4];
            short hx = bf16rn(v.x), hy = bf16rn(v.y), hz = bf16rn(v.z), hw = bf16rn(v.w);
            short lx = bf16rn(v.x - bf16tof(hx));
            short ly = bf16rn(v.y - bf16tof(hy));
            short lz = bf16rn(v.z - bf16tof(hz));
            short lw2 = bf16rn(v.w - bf16tof(hw));
            int2 hp, lp;
            hp.x = (int)(((unsigned)(unsigned short)hy << 16) | (unsigned short)hx);
            hp.y = (int)(((unsigned)(unsigned short)hw << 16) | (unsigned short)hz);
            lp.x = (int)(((unsigned)(unsigned short)ly << 16) | (unsigned short)lx);
            lp.y = (int)(((unsigned)(unsigned short)lw2 << 16) | (unsigned short)lz);
            *(int2*)&sHhi[row][f4 * 4] = hp;
            *(int2*)&sHlo[row][f4 * 4] = lp;
        }
        __syncthreads();

        short8v bhi[4], blo[4];
        #pragma unroll
        for (int j = 0; j < 4; ++j) {
            int col = wc * 64 + j * 16 + lrow;
            bhi[j] = *(const short8v*)&sWhi[col][lq * 8];
            blo[j] = *(const short8v*)&sWlo[col][lq * 8];
        }
        #pragma unroll
        for (int i = 0; i < 4; ++i) {
            int row = wr * 64 + i * 16 + lrow;
            short8v ahi = *(const short8v*)&sHhi[row][lq * 8];
            short8v alo = *(const short8v*)&sHlo[row][lq * 8];
            #pragma unroll
            for (int j = 0; j < 4; ++j) {
                // swapped: W frag in A-slot, H frag in B-slot -> D[c][node]
                acc[i][j] = __builtin_amdgcn_mfma_f32_16x16x32_bf16(bhi[j], ahi, acc[i][j], 0, 0, 0);
                acc[i][j] = __builtin_amdgcn_mfma_f32_16x16x32_bf16(blo[j], ahi, acc[i][j], 0, 0, 0);
                acc[i][j] = __builtin_amdgcn_mfma_f32_16x16x32_bf16(bhi[j], alo, acc[i][j], 0, 0, 0);
            }
        }
        __syncthreads();
    }

    // ---- epilogue: lane holds cols (wc*64+j*16+lq*4 .. +3) of node
    //      (r0+wr*64+i*16+lrow) -> coalesced float4 stores ----
    #pragma unroll
    for (int i = 0; i < 4; ++i) {
        int node = r0 + wr * 64 + i * 16 + lrow;
        if (node >= KN) continue;
        #pragma unroll
        for (int j = 0; j < 4; ++j) {
            int col = wc * 64 + j * 16 + lq * 4;
            float4 b4 = *(const float4*)&Bp[col];
            f32x4 a = acc[i][j];
            float4 v;
            v.x = a[0] + b4.x; v.y = a[1] + b4.y;
            v.z = a[2] + b4.z; v.w = a[3] + b4.w;
            if (relu) {
                v.x = fmaxf(v.x, 0.f); v.y = fmaxf(v.y, 0.f);
                v.z = fmaxf(v.z, 0.f); v.w = fmaxf(v.w, 0.f);
            }
            if (mode == 0) {
                *(float4*)&out_agg[((long)z * KN + node) * KH + col] = v;
            } else {
                long off = (long)t * KNT * KH + (et == 0 ? (long)KN * KH : 0)
                         + (long)node * KH + col;
                *(float4*)&d_out[off] = v;
            }
        }
    }
}

// ---------------------------------------------------------------------------
extern "C" void kernel_launch(void* const* d_in, const int* in_sizes, int n_in,
                              void* d_out_v, int out_size, void* d_ws, size_t ws_size,
                              hipStream_t stream) {
    const float* x_a    = (const float*)d_in[0];
    const float* x_d    = (const float*)d_in[1];
    const float* ea_ad  = (const float*)d_in[2];
    const float* ea_da  = (const float*)d_in[3];
    const int*   ei_ad  = (const int*)d_in[4];
    const int*   ei_da  = (const int*)d_in[5];
    const float* w1_ad  = (const float*)d_in[6];
    const float* b1_ad  = (const float*)d_in[7];
    const float* w2_ad  = (const float*)d_in[8];
    const float* b2_ad  = (const float*)d_in[9];
    const float* eps_ad = (const float*)d_in[10];
    const float* w1_da  = (const float*)d_in[11];
    const float* b1_da  = (const float*)d_in[12];
    const float* w2_da  = (const float*)d_in[13];
    const float* b2_da  = (const float*)d_in[14];
    const float* eps_da = (const float*)d_in[15];
    float* out = (float*)d_out_v;

    // workspace layout
    float* agg  = (float*)d_ws;                          // 8 * KN * KH floats
    int*   offs = (int*)(agg + (size_t)8 * KN * KH);     // 8 * (KN+1)
    int*   cur  = offs + (size_t)8 * (KN + 1);           // 8 * KN
    int2*  pes  = (int2*)(cur + (size_t)8 * KN);         // 8 * KE int2
    short* wsp  = (short*)(pes + (size_t)8 * KE);        // 32*2*4*4096 shorts = 2MB

    hipMemsetAsync(cur, 0, (size_t)8 * KN * sizeof(int), stream);
    wsplit_k<<<256, 256, 0, stream>>>(w1_ad, w1_da, w2_ad, w2_da, wsp);

    dim3 eg((KE + 255) / 256, 8);
    count_k<<<eg, 256, 0, stream>>>(ei_ad, ei_da, cur);
    scan_k<<<8, 256, 0, stream>>>(cur, offs);
    fill_k<<<eg, 256, 0, stream>>>(ei_ad, ei_da, cur, pes);

    dim3 ag(KN / 8, 8);                  // 2500 x 8, exact
    dim3 gg((KN + 127) / 128, 8);        // 157 x 8

    for (int l = 0; l < KL; ++l) {
        const float* xab; long xats;
        const float* xdb; long xdts;
        if (l == 0) {
            xab = x_a; xats = (long)KN * KH;
            xdb = x_d; xdts = (long)KN * KH;
        } else {
            xab = out;                 xats = (long)KNT * KH;
            xdb = out + (long)KN * KH; xdts = (long)KNT * KH;
        }
        agg_k<<<ag, 256, 0, stream>>>(xab, xats, xdb, xdts,
                                      ea_ad, ea_da,
                                      eps_ad, eps_da, offs, pes, agg, l);
        // mid = relu(H @ w1 + b1), in-place into agg
        gemm_k<<<gg, 256, 0, stream>>>(agg, wsp, b1_ad, b1_da,
                                       agg, out, l, 0, 1, 0);
        // x_new = mid @ w2 + b2 (+relu between layers), into d_out
        gemm_k<<<gg, 256, 0, stream>>>(agg, wsp, b2_ad, b2_da,
                                       agg, out, l, 1, (l == 0) ? 1 : 0, 1);
    }
}